// Round 2
// baseline (65.194 us; speedup 1.0000x reference)
//
#include <hip/hip_runtime.h>
#include <math.h>

#define BB 4
#define LL 5
#define CC 64
#define HH 128
#define WW 256
#define NTOT 16
#define CG 8  // channels per block
#define HW (HH * WW)

__global__ __launch_bounds__(256) void maxfusion_kernel(
    const float* __restrict__ x,        // (NTOT, C, H, W)
    const int* __restrict__ record_len, // (B,)
    const float* __restrict__ t,        // (B, L, L, 4, 4)
    float* __restrict__ out)            // (B, C, H, W)
{
    const int bid = blockIdx.x;
    const int h   = bid % HH;
    const int tmp = bid / HH;
    const int cg  = tmp % (CC / CG);
    const int b   = tmp / (CC / CG);
    const int w   = threadIdx.x;

    const int rl = record_len[b];
    int off = 0;
    #pragma unroll
    for (int i = 0; i < BB; ++i) off += (i < b) ? record_len[i] : 0;

    const float gx = -1.0f + 2.0f * (float)w / (float)(WW - 1);
    const float gy = -1.0f + 2.0f * (float)h / (float)(HH - 1);

    float maxv[CG];
    #pragma unroll
    for (int c = 0; c < CG; ++c) maxv[c] = -INFINITY;

    #pragma unroll
    for (int l = 0; l < LL; ++l) {
        const bool lv = (l < rl);  // wave-uniform predicate, no branch

        const float* tm = t + (size_t)(((b * LL + 0) * LL + l) * 16);
        const float m00 = tm[0];
        const float m01 = tm[1] * ((float)HH / (float)WW);
        const float m02 = tm[3] * (2.0f / (2.0f * 0.4f * (float)WW));
        const float m10 = tm[4] * ((float)WW / (float)HH);
        const float m11 = tm[5];
        const float m12 = tm[7] * (2.0f / (2.0f * 0.4f * (float)HH));

        const float g0 = m00 * gx + m01 * gy + m02;
        const float g1 = m10 * gx + m11 * gy + m12;
        const float ix = (g0 + 1.0f) * 0.5f * (float)(WW - 1);
        const float iy = (g1 + 1.0f) * 0.5f * (float)(HH - 1);

        const float x0f = floorf(ix), y0f = floorf(iy);
        const float wx1 = ix - x0f, wx0 = 1.0f - wx1;
        const float wy1 = iy - y0f, wy0 = 1.0f - wy1;
        const int x0 = (int)x0f, y0 = (int)y0f;
        const int x1 = x0 + 1,   y1 = y0 + 1;

        const bool vx0 = (x0 >= 0) && (x0 <= WW - 1);
        const bool vx1 = (x1 >= 0) && (x1 <= WW - 1);
        const bool vy0 = (y0 >= 0) && (y0 <= HH - 1);
        const bool vy1 = (y1 >= 0) && (y1 <= HH - 1);

        const int xc0 = min(max(x0, 0), WW - 1);
        const int xc1 = min(max(x1, 0), WW - 1);
        const int yc0 = min(max(y0, 0), HH - 1);
        const int yc1 = min(max(y1, 0), HH - 1);

        const float w00 = wx0 * wy0 * ((vx0 && vy0) ? 1.0f : 0.0f);
        const float w10 = wx1 * wy0 * ((vx1 && vy0) ? 1.0f : 0.0f);
        const float w01 = wx0 * wy1 * ((vx0 && vy1) ? 1.0f : 0.0f);
        const float w11 = wx1 * wy1 * ((vx1 && vy1) ? 1.0f : 0.0f);

        const int s00 = yc0 * WW + xc0;
        const int s10 = yc0 * WW + xc1;
        const int s01 = yc1 * WW + xc0;
        const int s11 = yc1 * WW + xc1;

        // Clamped index: loads for invalid agents hit images that other
        // blocks fetch anyway (L2/L3 hit), no extra HBM traffic.
        const int n = min(off + l, NTOT - 1);
        const float* base = x + ((size_t)n * CC + (size_t)cg * CG) * HW;

        #pragma unroll
        for (int c = 0; c < CG; ++c) {
            const float* p = base + (size_t)c * HW;
            float v = p[s00] * w00 + p[s10] * w10
                    + p[s01] * w01 + p[s11] * w11;
            v = lv ? v : -INFINITY;   // predicate, keep basic block straight
            maxv[c] = fmaxf(maxv[c], v);
        }
    }

    float* ob = out + (((size_t)b * CC + (size_t)cg * CG) * HH + h) * WW + w;
    #pragma unroll
    for (int c = 0; c < CG; ++c) {
        ob[(size_t)c * HW] = maxv[c];
    }
}

extern "C" void kernel_launch(void* const* d_in, const int* in_sizes, int n_in,
                              void* d_out, int out_size, void* d_ws, size_t ws_size,
                              hipStream_t stream) {
    const float* x          = (const float*)d_in[0];
    const int*   record_len = (const int*)d_in[1];
    const float* t          = (const float*)d_in[2];
    float* out = (float*)d_out;

    const int blocks = BB * (CC / CG) * HH;  // 4096
    maxfusion_kernel<<<blocks, 256, 0, stream>>>(x, record_len, t, out);
}

// Round 3
// 57.446 us; speedup vs baseline: 1.1349x; 1.1349x over previous
//
#include <hip/hip_runtime.h>
#include <math.h>

#define BB 4
#define LL 5
#define CC 64
#define HH 128
#define WW 256
#define NTOT 16
#define CG 8  // channels per block
#define HW (HH * WW)

__global__ __launch_bounds__(256) void maxfusion_kernel(
    const float* __restrict__ x,        // (NTOT, C, H, W)
    const int* __restrict__ record_len, // (B,)
    const float* __restrict__ t,        // (B, L, L, 4, 4)
    float* __restrict__ out)            // (B, C, H, W)
{
    const int bid = blockIdx.x;
    const int h   = bid % HH;
    const int tmp = bid / HH;
    const int cg  = tmp % (CC / CG);
    const int b   = tmp / (CC / CG);
    const int w   = threadIdx.x;

    const int rl = record_len[b];
    int off = 0;
    #pragma unroll
    for (int i = 0; i < BB; ++i) off += (i < b) ? record_len[i] : 0;

    const float gx = -1.0f + 2.0f * (float)w / (float)(WW - 1);
    const float gy = -1.0f + 2.0f * (float)h / (float)(HH - 1);

    float maxv[CG];
    #pragma unroll
    for (int c = 0; c < CG; ++c) maxv[c] = -INFINITY;

    for (int l = 0; l < rl; ++l) {
        // t[b, 0, l] — uniform across the block: scalar loads + SGPR math.
        const float* tm = t + (size_t)((b * LL * LL + l) * 16);
        const float m00 = tm[0];
        const float m01 = tm[1] * ((float)HH / (float)WW);
        const float m02 = tm[3] * (2.0f / (0.8f * (float)WW));
        const float m10 = tm[4] * ((float)WW / (float)HH);
        const float m11 = tm[5];
        const float m12 = tm[7] * (2.0f / (0.8f * (float)HH));
        // fold grid->pixel scaling: ix = (g0+1)*0.5*(W-1), uniform coeffs
        const float sx  = 0.5f * (float)(WW - 1);
        const float sy  = 0.5f * (float)(HH - 1);
        const float a00 = m00 * sx, a01 = m01 * sx, a02 = (m02 + 1.0f) * sx;
        const float a10 = m10 * sy, a11 = m11 * sy, a12 = (m12 + 1.0f) * sy;

        const float ix = a00 * gx + a01 * gy + a02;
        const float iy = a10 * gx + a11 * gy + a12;

        const float x0f = floorf(ix), y0f = floorf(iy);
        const float wx1 = ix - x0f, wx0 = 1.0f - wx1;
        const float wy1 = iy - y0f, wy0 = 1.0f - wy1;
        const int x0 = (int)x0f, y0 = (int)y0f;

        // Pair-weights for the float2 at column k=clamp(x0,0,W-2):
        //   wxa applies to .x (col k), wxb to .y (col k+1).
        // Covers interior, x0==-1 (only x1 valid), x0==W-1 (only x0 valid),
        // and fully-out-of-range (both zero) — exact zero-padding semantics.
        const bool inx = (x0 >= 0) && (x0 <= WW - 2);
        const float wxa = inx ? wx0 : ((x0 == -1)     ? wx1 : 0.0f);
        const float wxb = inx ? wx1 : ((x0 == WW - 1) ? wx0 : 0.0f);
        const float wy0v = ((y0 >= 0)     && (y0 <= HH - 1))     ? wy0 : 0.0f;
        const float wy1v = ((y0 + 1 >= 0) && (y0 + 1 <= HH - 1)) ? wy1 : 0.0f;

        const int k  = min(max(x0, 0), WW - 2);
        const int r0 = min(max(y0,     0), HH - 1);
        const int r1 = min(max(y0 + 1, 0), HH - 1);
        const int off0 = r0 * WW + k;
        const int off1 = r1 * WW + k;

        const int n = min(off + l, NTOT - 1);
        const float* base = x + ((size_t)n * CC + (size_t)cg * CG) * HW;

        #pragma unroll
        for (int c = 0; c < CG; ++c) {
            const float* p = base + (size_t)c * HW;
            const float2 q0 = *reinterpret_cast<const float2*>(p + off0);
            const float2 q1 = *reinterpret_cast<const float2*>(p + off1);
            float t0 = q0.x * wxa + q0.y * wxb;
            float t1 = q1.x * wxa + q1.y * wxb;
            float v  = t0 * wy0v + t1 * wy1v;
            maxv[c] = fmaxf(maxv[c], v);
        }
    }

    float* ob = out + (((size_t)b * CC + (size_t)cg * CG) * HH + h) * WW + w;
    #pragma unroll
    for (int c = 0; c < CG; ++c) {
        ob[(size_t)c * HW] = maxv[c];
    }
}

extern "C" void kernel_launch(void* const* d_in, const int* in_sizes, int n_in,
                              void* d_out, int out_size, void* d_ws, size_t ws_size,
                              hipStream_t stream) {
    const float* x          = (const float*)d_in[0];
    const int*   record_len = (const int*)d_in[1];
    const float* t          = (const float*)d_in[2];
    float* out = (float*)d_out;

    const int blocks = BB * (CC / CG) * HH;  // 4096
    maxfusion_kernel<<<blocks, 256, 0, stream>>>(x, record_len, t, out);
}

// Round 4
// 46.577 us; speedup vs baseline: 1.3997x; 1.2334x over previous
//
#include <hip/hip_runtime.h>
#include <math.h>

#define BB 4
#define LL 5
#define CC 64
#define HH 128
#define WW 256
#define NTOT 16
#define CG 8  // channels per block
#define HW (HH * WW)
#define NXCD 8
#define NWG (BB * (CC / CG) * HH)  // 4096, divisible by 8

__global__ __launch_bounds__(256) void maxfusion_kernel(
    const float* __restrict__ x,        // (NTOT, C, H, W)
    const int* __restrict__ record_len, // (B,)
    const float* __restrict__ t,        // (B, L, L, 4, 4)
    float* __restrict__ out)            // (B, C, H, W)
{
    // XCD-aware swizzle: hardware round-robins blockIdx across 8 XCDs.
    // logical = (bid%8)*(NWG/8) + bid/8 gives each XCD a contiguous chunk
    // of 512 logical blocks = 4 full (b,cg) panels (all 128 h-rows), so
    // channel-plane fetches stay in ONE XCD's L2 and h<->h+1 row reuse hits.
    const int bid = (blockIdx.x % NXCD) * (NWG / NXCD) + blockIdx.x / NXCD;

    const int h   = bid % HH;
    const int tmp = bid / HH;
    const int cg  = tmp % (CC / CG);
    const int b   = tmp / (CC / CG);
    const int w   = threadIdx.x;

    const int rl = record_len[b];
    int off = 0;
    #pragma unroll
    for (int i = 0; i < BB; ++i) off += (i < b) ? record_len[i] : 0;

    const float gx = -1.0f + 2.0f * (float)w / (float)(WW - 1);
    const float gy = -1.0f + 2.0f * (float)h / (float)(HH - 1);

    float maxv[CG];
    #pragma unroll
    for (int c = 0; c < CG; ++c) maxv[c] = -INFINITY;

    for (int l = 0; l < rl; ++l) {
        // t[b, 0, l] — uniform across the block: scalar loads + SGPR math.
        const float* tm = t + (size_t)((b * LL * LL + l) * 16);
        const float m00 = tm[0];
        const float m01 = tm[1] * ((float)HH / (float)WW);
        const float m02 = tm[3] * (2.0f / (0.8f * (float)WW));
        const float m10 = tm[4] * ((float)WW / (float)HH);
        const float m11 = tm[5];
        const float m12 = tm[7] * (2.0f / (0.8f * (float)HH));
        const float sx  = 0.5f * (float)(WW - 1);
        const float sy  = 0.5f * (float)(HH - 1);
        const float a00 = m00 * sx, a01 = m01 * sx, a02 = (m02 + 1.0f) * sx;
        const float a10 = m10 * sy, a11 = m11 * sy, a12 = (m12 + 1.0f) * sy;

        const float ix = a00 * gx + a01 * gy + a02;
        const float iy = a10 * gx + a11 * gy + a12;

        const float x0f = floorf(ix), y0f = floorf(iy);
        const float wx1 = ix - x0f, wx0 = 1.0f - wx1;
        const float wy1 = iy - y0f, wy0 = 1.0f - wy1;
        const int x0 = (int)x0f, y0 = (int)y0f;

        const bool inx = (x0 >= 0) && (x0 <= WW - 2);
        const float wxa = inx ? wx0 : ((x0 == -1)     ? wx1 : 0.0f);
        const float wxb = inx ? wx1 : ((x0 == WW - 1) ? wx0 : 0.0f);
        const float wy0v = ((y0 >= 0)     && (y0 <= HH - 1))     ? wy0 : 0.0f;
        const float wy1v = ((y0 + 1 >= 0) && (y0 + 1 <= HH - 1)) ? wy1 : 0.0f;

        const int k  = min(max(x0, 0), WW - 2);
        const int r0 = min(max(y0,     0), HH - 1);
        const int r1 = min(max(y0 + 1, 0), HH - 1);
        const int off0 = r0 * WW + k;
        const int off1 = r1 * WW + k;

        const int n = min(off + l, NTOT - 1);
        const float* base = x + ((size_t)n * CC + (size_t)cg * CG) * HW;

        #pragma unroll
        for (int c = 0; c < CG; ++c) {
            const float* p = base + (size_t)c * HW;
            const float2 q0 = *reinterpret_cast<const float2*>(p + off0);
            const float2 q1 = *reinterpret_cast<const float2*>(p + off1);
            float t0 = q0.x * wxa + q0.y * wxb;
            float t1 = q1.x * wxa + q1.y * wxb;
            float v  = t0 * wy0v + t1 * wy1v;
            maxv[c] = fmaxf(maxv[c], v);
        }
    }

    float* ob = out + (((size_t)b * CC + (size_t)cg * CG) * HH + h) * WW + w;
    #pragma unroll
    for (int c = 0; c < CG; ++c) {
        __builtin_nontemporal_store(maxv[c], ob + (size_t)c * HW);
    }
}

extern "C" void kernel_launch(void* const* d_in, const int* in_sizes, int n_in,
                              void* d_out, int out_size, void* d_ws, size_t ws_size,
                              hipStream_t stream) {
    const float* x          = (const float*)d_in[0];
    const int*   record_len = (const int*)d_in[1];
    const float* t          = (const float*)d_in[2];
    float* out = (float*)d_out;

    maxfusion_kernel<<<NWG, 256, 0, stream>>>(x, record_len, t, out);
}